// Round 2
// baseline (774.609 us; speedup 1.0000x reference)
//
#include <hip/hip_runtime.h>
#include <hip/hip_bf16.h>
#include <math.h>

// CVQNN classifier, N=64 modes, OUT=10, HBAR=2.
// Kernel 1 (1 block, 192 thr): build S (128x128 symplectic, 2 layers) and d.
//   Thread c holds column c of S in registers (ops are column-local).
//   Thread 128 carries the displacement vector d through the same ops.
//   Emits to ws: W[k][rr] = 2*S[rows[rr],k] (k<64, 1280 fl),
//                bias[rr] = d[rows[rr]] (20 fl), cterm[w] (10 fl).
// Kernel 2: W/bias/cterm in LDS (uniform-address broadcast reads).
//   2 rows per thread (W reads amortized 2x, 2x ILP), rolling dist-1
//   float4 prefetch of x (VGPR ~100, forced <=128 via launch_bounds ->
//   4 waves/SIMD vs round-1's 2), balanced grid (512 rows/block, no
//   grid-stride). Round-1 bottleneck was exposed LDS/HBM latency at
//   2 waves/SIMD + grid imbalance (VALUBusy 18%, occ 11%).

#define TWO_N 128
#define OUT_N 10
#define LSTRIDE 758
// per-layer trig table layout (stride 758):
// [0,63) ct1 [63,126) st1 [126,189) cp1 [189,252) sp1
// [252,315) rot_c [315,378) rot_s [378,442) exp(-sq) [442,506) exp(+sq)
// [506,758) int2 trig (same sublayout as int1)

template<int S>
__device__ __forceinline__ void bs_apply(float (&col)[TWO_N], const float* t){
  #pragma unroll
  for (int i = S; i < 63; i += 2){
    float ct = t[i], st = t[63+i], cp = t[126+i], sp = t[189+i];
    float cs = cp*st, ss = sp*st;
    float a = col[i], b = col[i+1], e = col[64+i], f = col[65+i];
    col[i]    = ct*a - cs*b - ss*f;
    col[i+1]  = cs*a + ct*b - ss*e;
    col[64+i] = ss*b + ct*e - cs*f;
    col[65+i] = ss*a + cs*e + ct*f;
  }
}

__device__ __forceinline__ void rot_squeeze(float (&col)[TWO_N], const float* t){
  #pragma unroll
  for (int m = 0; m < 64; ++m){
    float cm = (m < 63) ? t[252+m] : 1.0f;
    float sm = (m < 63) ? t[315+m] : 0.0f;
    float em = t[378+m], ep = t[442+m];
    float u = col[m], v = col[64+m];
    col[m]    = em * (cm*u - sm*v);
    col[64+m] = ep * (sm*u + cm*v);
  }
}

__global__ __launch_bounds__(192, 1)
void cvqnn_setup(const float* __restrict__ i1_0, const float* __restrict__ sq_0,
                 const float* __restrict__ i2_0, const float* __restrict__ dp_0,
                 const float* __restrict__ i1_1, const float* __restrict__ sq_1,
                 const float* __restrict__ i2_1, const float* __restrict__ dp_1,
                 float* __restrict__ ws)
{
  __shared__ float trig[2*LSTRIDE];
  __shared__ float red[128*OUT_N];
  const int tid = threadIdx.x;

  // ---- parallel transcendental precompute ----
  for (int idx = tid; idx < 2*LSTRIDE; idx += 192){
    int L = idx / LSTRIDE, q = idx - L*LSTRIDE;
    const float* i1 = L ? i1_1 : i1_0;
    const float* i2 = L ? i2_1 : i2_0;
    const float* sq = L ? sq_1 : sq_0;
    float v;
    if (q < 252){
      int kind = q / 63, i = q - kind*63;
      float ang = (kind & 2) ? i1[3*i+1] : i1[3*i];
      v = (kind & 1) ? sinf(ang) : cosf(ang);
    } else if (q < 378){
      int kind = (q-252)/63, m = (q-252) - kind*63;
      float ang = i1[3*m+2];
      v = kind ? sinf(ang) : cosf(ang);
    } else if (q < 506){
      int kind = (q-378)/64, m = (q-378) - kind*64;
      v = expf(kind ? sq[m] : -sq[m]);
    } else {
      int qq = q - 506;
      int kind = qq / 63, i = qq - kind*63;
      float ang = (kind & 2) ? i2[3*i+1] : i2[3*i];
      v = (kind & 1) ? sinf(ang) : cosf(ang);
    }
    trig[idx] = v;
  }
  __syncthreads();

  // ---- column-local transform (no syncs needed: ops mix rows, not cols) ----
  float col[TWO_N];
  const int c = tid;
  if (c < 129){
    #pragma unroll
    for (int r = 0; r < TWO_N; ++r) col[r] = (r == c) ? 1.0f : 0.0f; // c==128 -> zeros (d)

    #pragma unroll
    for (int L = 0; L < 2; ++L){
      const float* tl = trig + L*LSTRIDE;
      bs_apply<0>(col, tl);
      bs_apply<1>(col, tl);
      rot_squeeze(col, tl);
      bs_apply<0>(col, tl + 506);
      bs_apply<1>(col, tl + 506);
      if (c == 128){
        const float* dp = L ? dp_1 : dp_0;
        #pragma unroll
        for (int m = 0; m < 64; ++m) col[m] += 2.0f * dp[m];
      }
    }

    // rows of interest: rr<10 -> row rr ; rr>=10 -> row 64+(rr-10) = 54+rr
    if (c < 64){
      #pragma unroll
      for (int rr = 0; rr < 20; ++rr){
        int row = (rr < 10) ? rr : (54 + rr);
        ws[c*20 + rr] = 2.0f * col[row];   // W[k=c][rr], factor 2 folded in
      }
    }
    if (c < 128){
      #pragma unroll
      for (int w = 0; w < OUT_N; ++w)
        red[c*OUT_N + w] = col[w]*col[w] + col[64+w]*col[64+w];
    }
    if (c == 128){
      #pragma unroll
      for (int rr = 0; rr < 20; ++rr){
        int row = (rr < 10) ? rr : (54 + rr);
        ws[1280 + rr] = col[row];          // bias = d[rows]
      }
    }
  }
  __syncthreads();
  if (tid < OUT_N){
    float s = 0.0f;
    for (int k = 0; k < 128; ++k) s += red[k*OUT_N + tid];
    ws[1300 + tid] = s;                    // cov_term[w]
  }
}

// one float4 of weights, one x scalar per row, 8 FMAs
#define QFMA(M, WV, XA, XB) {                                   \
    float4 wm_ = (WV)[M];                                       \
    acc0[4*(M)+0] = fmaf((XA), wm_.x, acc0[4*(M)+0]);           \
    acc0[4*(M)+1] = fmaf((XA), wm_.y, acc0[4*(M)+1]);           \
    acc0[4*(M)+2] = fmaf((XA), wm_.z, acc0[4*(M)+2]);           \
    acc0[4*(M)+3] = fmaf((XA), wm_.w, acc0[4*(M)+3]);           \
    acc1[4*(M)+0] = fmaf((XB), wm_.x, acc1[4*(M)+0]);           \
    acc1[4*(M)+1] = fmaf((XB), wm_.y, acc1[4*(M)+1]);           \
    acc1[4*(M)+2] = fmaf((XB), wm_.z, acc1[4*(M)+2]);           \
    acc1[4*(M)+3] = fmaf((XB), wm_.w, acc1[4*(M)+3]);           \
  }

#define QSTEP(Q, XA, XB) {                                              \
    const float4* wv_ = reinterpret_cast<const float4*>(wb + (Q)*20);   \
    QFMA(0, wv_, XA, XB); QFMA(1, wv_, XA, XB); QFMA(2, wv_, XA, XB);   \
    QFMA(3, wv_, XA, XB); QFMA(4, wv_, XA, XB);                         \
  }

__global__ __launch_bounds__(256, 4)
void cvqnn_main(const float* __restrict__ x, const float* __restrict__ ws,
                float* __restrict__ out, int B)
{
  // shs: [0,1280) W (layout k*20+rr), [1280,1300) bias, [1300,1310) cterm
  __shared__ float shs[1310];
  const int tid = threadIdx.x;
  #pragma unroll
  for (int i = 0; i < 6; ++i){
    int idx = i*256 + tid;
    if (idx < 1310) shs[idx] = ws[idx];
  }
  __syncthreads();

  const int base = blockIdx.x * 512;
  const int b0 = base + tid;
  const int b1 = base + 256 + tid;
  const bool v0 = b0 < B, v1 = b1 < B;
  // clamp OOB rows to row 0: loads stay in-bounds, results never stored
  const int rb0 = v0 ? b0 : 0;
  const int rb1 = v1 ? b1 : 0;

  const float4* x40 = reinterpret_cast<const float4*>(x) + ((size_t)rb0 << 4);
  const float4* x41 = reinterpret_cast<const float4*>(x) + ((size_t)rb1 << 4);

  float acc0[20], acc1[20];
  #pragma unroll
  for (int r = 0; r < 20; ++r){ float bv = shs[1280 + r]; acc0[r] = bv; acc1[r] = bv; }

  float4 c0 = x40[0], c1 = x41[0];

  #pragma unroll 4
  for (int k4 = 0; k4 < 16; ++k4){
    float4 n0, n1;
    if (k4 < 15){ n0 = x40[k4+1]; n1 = x41[k4+1]; }   // dist-1 prefetch
    const float* wb = shs + k4*80;
    QSTEP(0, c0.x, c1.x);
    QSTEP(1, c0.y, c1.y);
    QSTEP(2, c0.z, c1.z);
    QSTEP(3, c0.w, c1.w);
    if (k4 < 15){ c0 = n0; c1 = n1; }
  }

  #pragma unroll
  for (int rowp = 0; rowp < 2; ++rowp){
    const float* acc = rowp ? acc1 : acc0;
    const bool   vv  = rowp ? v1 : v0;
    const int    bb  = rowp ? b1 : b0;
    if (vv){
      float2* o = reinterpret_cast<float2*>(out + (size_t)bb * 10);
      #pragma unroll
      for (int w = 0; w < OUT_N; w += 2){
        float mx0 = acc[w],   mp0 = acc[10+w];
        float nm0 = (shs[1300+w] + mx0*mx0 + mp0*mp0) * 0.25f - 0.5f;
        float r0  = log1pf(fmaxf(nm0, 0.0f));
        float mx1 = acc[w+1], mp1 = acc[11+w];
        float nm1 = (shs[1301+w] + mx1*mx1 + mp1*mp1) * 0.25f - 0.5f;
        float r1  = log1pf(fmaxf(nm1, 0.0f));
        o[w >> 1] = make_float2(r0, r1);
      }
    }
  }
}

extern "C" void kernel_launch(void* const* d_in, const int* in_sizes, int n_in,
                              void* d_out, int out_size, void* d_ws, size_t ws_size,
                              hipStream_t stream)
{
  const float* x    = (const float*)d_in[0];
  const float* i1_0 = (const float*)d_in[1];
  const float* sq_0 = (const float*)d_in[2];
  const float* i2_0 = (const float*)d_in[3];
  const float* dp_0 = (const float*)d_in[4];
  const float* i1_1 = (const float*)d_in[5];
  const float* sq_1 = (const float*)d_in[6];
  const float* i2_1 = (const float*)d_in[7];
  const float* dp_1 = (const float*)d_in[8];
  float* ws = (float*)d_ws;

  int B = in_sizes[0] / 64;

  cvqnn_setup<<<1, 192, 0, stream>>>(i1_0, sq_0, i2_0, dp_0,
                                     i1_1, sq_1, i2_1, dp_1, ws);

  int grid = (B + 511) / 512;   // 512 rows per block, balanced, no grid-stride
  cvqnn_main<<<grid, 256, 0, stream>>>(x, ws, (float*)d_out, B);
}

// Round 3
// 443.399 us; speedup vs baseline: 1.7470x; 1.7470x over previous
//
#include <hip/hip_runtime.h>
#include <hip/hip_bf16.h>
#include <math.h>

// CVQNN classifier, N=64 modes, OUT=10, HBAR=2.
// Kernel 1 (1 block, 192 thr): build S (128x128 symplectic, 2 layers) and d.
//   Thread c holds column c of S in registers (ops are column-local).
//   Thread 128 carries the displacement vector d through the same ops.
//   Emits to ws: W[k][rr] = 2*S[rows[rr],k] (k<64, 1280 fl),
//                bias[rr] = d[rows[rr]] (20 fl), cterm[w] (10 fl).
// Kernel 2: W/bias/cterm in LDS (uniform-address broadcast reads, ~free).
//   ONE row per thread: acc[20]+c+n+addr ~45 live VGPRs -> fits the 64-reg
//   cap that __launch_bounds__(256,4) empirically imposes (round 2 lesson:
//   (256,4) => 64-reg cap; 2-row version needed ~85 and SPILLED, causing
//   1.25GB fetch / 0.84GB write of scratch traffic at 53% HBM peak).
//   #pragma unroll 1 on the k4 loop stops the scheduler from hoisting 16
//   iterations of loads (round-1's 196-reg bloat). Latency hiding comes
//   from occupancy (8 waves/SIMD at 64 regs), not deep unrolling.

#define TWO_N 128
#define OUT_N 10
#define LSTRIDE 758
// per-layer trig table layout (stride 758):
// [0,63) ct1 [63,126) st1 [126,189) cp1 [189,252) sp1
// [252,315) rot_c [315,378) rot_s [378,442) exp(-sq) [442,506) exp(+sq)
// [506,758) int2 trig (same sublayout as int1)

template<int S>
__device__ __forceinline__ void bs_apply(float (&col)[TWO_N], const float* t){
  #pragma unroll
  for (int i = S; i < 63; i += 2){
    float ct = t[i], st = t[63+i], cp = t[126+i], sp = t[189+i];
    float cs = cp*st, ss = sp*st;
    float a = col[i], b = col[i+1], e = col[64+i], f = col[65+i];
    col[i]    = ct*a - cs*b - ss*f;
    col[i+1]  = cs*a + ct*b - ss*e;
    col[64+i] = ss*b + ct*e - cs*f;
    col[65+i] = ss*a + cs*e + ct*f;
  }
}

__device__ __forceinline__ void rot_squeeze(float (&col)[TWO_N], const float* t){
  #pragma unroll
  for (int m = 0; m < 64; ++m){
    float cm = (m < 63) ? t[252+m] : 1.0f;
    float sm = (m < 63) ? t[315+m] : 0.0f;
    float em = t[378+m], ep = t[442+m];
    float u = col[m], v = col[64+m];
    col[m]    = em * (cm*u - sm*v);
    col[64+m] = ep * (sm*u + cm*v);
  }
}

__global__ __launch_bounds__(192, 1)
void cvqnn_setup(const float* __restrict__ i1_0, const float* __restrict__ sq_0,
                 const float* __restrict__ i2_0, const float* __restrict__ dp_0,
                 const float* __restrict__ i1_1, const float* __restrict__ sq_1,
                 const float* __restrict__ i2_1, const float* __restrict__ dp_1,
                 float* __restrict__ ws)
{
  __shared__ float trig[2*LSTRIDE];
  __shared__ float red[128*OUT_N];
  const int tid = threadIdx.x;

  // ---- parallel transcendental precompute ----
  for (int idx = tid; idx < 2*LSTRIDE; idx += 192){
    int L = idx / LSTRIDE, q = idx - L*LSTRIDE;
    const float* i1 = L ? i1_1 : i1_0;
    const float* i2 = L ? i2_1 : i2_0;
    const float* sq = L ? sq_1 : sq_0;
    float v;
    if (q < 252){
      int kind = q / 63, i = q - kind*63;
      float ang = (kind & 2) ? i1[3*i+1] : i1[3*i];
      v = (kind & 1) ? sinf(ang) : cosf(ang);
    } else if (q < 378){
      int kind = (q-252)/63, m = (q-252) - kind*63;
      float ang = i1[3*m+2];
      v = kind ? sinf(ang) : cosf(ang);
    } else if (q < 506){
      int kind = (q-378)/64, m = (q-378) - kind*64;
      v = expf(kind ? sq[m] : -sq[m]);
    } else {
      int qq = q - 506;
      int kind = qq / 63, i = qq - kind*63;
      float ang = (kind & 2) ? i2[3*i+1] : i2[3*i];
      v = (kind & 1) ? sinf(ang) : cosf(ang);
    }
    trig[idx] = v;
  }
  __syncthreads();

  // ---- column-local transform (no syncs needed: ops mix rows, not cols) ----
  float col[TWO_N];
  const int c = tid;
  if (c < 129){
    #pragma unroll
    for (int r = 0; r < TWO_N; ++r) col[r] = (r == c) ? 1.0f : 0.0f; // c==128 -> zeros (d)

    #pragma unroll
    for (int L = 0; L < 2; ++L){
      const float* tl = trig + L*LSTRIDE;
      bs_apply<0>(col, tl);
      bs_apply<1>(col, tl);
      rot_squeeze(col, tl);
      bs_apply<0>(col, tl + 506);
      bs_apply<1>(col, tl + 506);
      if (c == 128){
        const float* dp = L ? dp_1 : dp_0;
        #pragma unroll
        for (int m = 0; m < 64; ++m) col[m] += 2.0f * dp[m];
      }
    }

    // rows of interest: rr<10 -> row rr ; rr>=10 -> row 64+(rr-10) = 54+rr
    if (c < 64){
      #pragma unroll
      for (int rr = 0; rr < 20; ++rr){
        int row = (rr < 10) ? rr : (54 + rr);
        ws[c*20 + rr] = 2.0f * col[row];   // W[k=c][rr], factor 2 folded in
      }
    }
    if (c < 128){
      #pragma unroll
      for (int w = 0; w < OUT_N; ++w)
        red[c*OUT_N + w] = col[w]*col[w] + col[64+w]*col[64+w];
    }
    if (c == 128){
      #pragma unroll
      for (int rr = 0; rr < 20; ++rr){
        int row = (rr < 10) ? rr : (54 + rr);
        ws[1280 + rr] = col[row];          // bias = d[rows]
      }
    }
  }
  __syncthreads();
  if (tid < OUT_N){
    float s = 0.0f;
    for (int k = 0; k < 128; ++k) s += red[k*OUT_N + tid];
    ws[1300 + tid] = s;                    // cov_term[w]
  }
}

__global__ __launch_bounds__(256, 4)
void cvqnn_main(const float* __restrict__ x, const float* __restrict__ ws,
                float* __restrict__ out, int B)
{
  // shs: [0,1280) W (layout k*20+rr), [1280,1300) bias, [1300,1310) cterm
  __shared__ __align__(16) float shs[1310];
  const int tid = threadIdx.x;
  #pragma unroll
  for (int i = 0; i < 6; ++i){
    int idx = i*256 + tid;
    if (idx < 1310) shs[idx] = ws[idx];
  }
  __syncthreads();

  const int b = blockIdx.x * 256 + tid;
  const bool v = b < B;
  const int rb = v ? b : 0;               // clamp OOB rows: load row 0, never store

  const float4* x4 = reinterpret_cast<const float4*>(x) + ((size_t)rb << 4);

  float acc[20];
  #pragma unroll
  for (int r = 0; r < 20; ++r) acc[r] = shs[1280 + r];   // bias (broadcast)

  float4 c = x4[0];

  #pragma unroll 1   // no cross-iteration hoisting: keep live set ~45 regs
  for (int k4 = 0; k4 < 16; ++k4){
    float4 n;
    if (k4 < 15) n = x4[k4 + 1];          // dist-1 prefetch
    const float* wb = shs + k4*80;        // uniform LDS address -> broadcast
    #pragma unroll
    for (int q = 0; q < 4; ++q){
      float xs = (q == 0) ? c.x : (q == 1) ? c.y : (q == 2) ? c.z : c.w;
      const float4* wv = reinterpret_cast<const float4*>(wb + q*20);
      #pragma unroll
      for (int m = 0; m < 5; ++m){
        float4 w = wv[m];
        acc[4*m+0] = fmaf(xs, w.x, acc[4*m+0]);
        acc[4*m+1] = fmaf(xs, w.y, acc[4*m+1]);
        acc[4*m+2] = fmaf(xs, w.z, acc[4*m+2]);
        acc[4*m+3] = fmaf(xs, w.w, acc[4*m+3]);
      }
    }
    if (k4 < 15) c = n;
  }

  if (v){
    float2* o = reinterpret_cast<float2*>(out + (size_t)b * 10); // 40B row, 8B aligned
    #pragma unroll
    for (int w = 0; w < OUT_N; w += 2){
      float mx0 = acc[w],   mp0 = acc[10+w];
      float nm0 = (shs[1300+w] + mx0*mx0 + mp0*mp0) * 0.25f - 0.5f;
      float r0  = log1pf(fmaxf(nm0, 0.0f));
      float mx1 = acc[w+1], mp1 = acc[11+w];
      float nm1 = (shs[1301+w] + mx1*mx1 + mp1*mp1) * 0.25f - 0.5f;
      float r1  = log1pf(fmaxf(nm1, 0.0f));
      o[w >> 1] = make_float2(r0, r1);
    }
  }
}

extern "C" void kernel_launch(void* const* d_in, const int* in_sizes, int n_in,
                              void* d_out, int out_size, void* d_ws, size_t ws_size,
                              hipStream_t stream)
{
  const float* x    = (const float*)d_in[0];
  const float* i1_0 = (const float*)d_in[1];
  const float* sq_0 = (const float*)d_in[2];
  const float* i2_0 = (const float*)d_in[3];
  const float* dp_0 = (const float*)d_in[4];
  const float* i1_1 = (const float*)d_in[5];
  const float* sq_1 = (const float*)d_in[6];
  const float* i2_1 = (const float*)d_in[7];
  const float* dp_1 = (const float*)d_in[8];
  float* ws = (float*)d_ws;

  int B = in_sizes[0] / 64;

  cvqnn_setup<<<1, 192, 0, stream>>>(i1_0, sq_0, i2_0, dp_0,
                                     i1_1, sq_1, i2_1, dp_1, ws);

  int grid = (B + 255) / 256;   // 256 rows per block, exact, balanced
  cvqnn_main<<<grid, 256, 0, stream>>>(x, ws, (float*)d_out, B);
}